// Round 1
// baseline (96.070 us; speedup 1.0000x reference)
//
#include <hip/hip_runtime.h>
#include <hip/hip_bf16.h>

// out[b, :] = (1/K) * sum_k embed[ids[b,k], :]
// B=8192, K=32, D=128, V=100000.
//
// Mapping: 32 lanes per row, lane c owns float4 chunk c of D (D/4 = 32 chunks).
// Block = 256 threads = 8 rows. Grid = B/8 = 1024 blocks.
// Ids are loaded coalesced (lane c loads id c of its row) then broadcast with
// __shfl within the 32-lane row group, so the k-loop is 32 independent
// global_load_dwordx4 ops per lane — pure gather bandwidth.

#define K_NEIGH 32
#define D4      32   // D/4 float4 chunks per row
#define ROWS_PER_BLOCK 8

__global__ __launch_bounds__(256) void mean_agg_kernel(
    const int* __restrict__ ids,        // [B, K] int32
    const float4* __restrict__ embed,   // [V, D/4] float4
    float4* __restrict__ out)           // [B, D/4] float4
{
    const int tid = threadIdx.x;
    const int row = blockIdx.x * ROWS_PER_BLOCK + (tid >> 5);
    const int c   = tid & 31;

    // Coalesced id load: lane c holds ids[row, c].
    const int my_id = ids[row * K_NEIGH + c];

    float4 acc = make_float4(0.f, 0.f, 0.f, 0.f);

#pragma unroll
    for (int k = 0; k < K_NEIGH; ++k) {
        const int id = __shfl(my_id, k, 32);      // broadcast within row group
        const float4 v = embed[(long)id * D4 + c];
        acc.x += v.x; acc.y += v.y; acc.z += v.z; acc.w += v.w;
    }

    const float s = 1.0f / (float)K_NEIGH;
    acc.x *= s; acc.y *= s; acc.z *= s; acc.w *= s;
    out[row * D4 + c] = acc;
}

extern "C" void kernel_launch(void* const* d_in, const int* in_sizes, int n_in,
                              void* d_out, int out_size, void* d_ws, size_t ws_size,
                              hipStream_t stream) {
    const int*    ids   = (const int*)d_in[0];      // [B, K] int32
    const float4* embed = (const float4*)d_in[1];   // [V, D/4]
    float4*       out   = (float4*)d_out;           // [B, D/4]

    const int B = 8192;
    dim3 grid(B / ROWS_PER_BLOCK);
    dim3 block(256);
    mean_agg_kernel<<<grid, block, 0, stream>>>(ids, embed, out);
}